// Round 1
// baseline (7151.283 us; speedup 1.0000x reference)
//
#include <hip/hip_runtime.h>

// WaveRNN: damped 2D wave equation, B=16, T=256, 256x256 grid, 3 probes.
// One workgroup (1024 threads = 16 waves) per batch; entire field pair held in
// VGPRs (16x4 cells/thread). One __syncthreads per step; halo rows through
// double-buffered LDS; halo cols through wave shuffles.

#define B_ 16
#define T_ 256
#define NX 256
#define NY 256
#define NP 3

__launch_bounds__(1024)
__global__ void wave_step_all(const float* __restrict__ xin,
                              const float* __restrict__ cin,
                              const float* __restrict__ bin,
                              const int* __restrict__ pxp,
                              const int* __restrict__ pyp,
                              const int* __restrict__ sxp,
                              const int* __restrict__ syp,
                              float* __restrict__ out)
{
    const int b   = blockIdx.x;        // batch
    const int tid = threadIdx.x;
    const int w   = tid >> 6;          // wave index 0..15 -> rows [w*16, w*16+16)
    const int l   = tid & 63;          // lane 0..63      -> cols [l*4,  l*4+4)
    const int x0  = w << 4;
    const int y0  = l << 2;

    __shared__ float xbuf[T_];
    // halo row buffers, double-buffered by step parity.
    // topB[p][s][*]: s in 0..16, slot s = TOP row of wave s; slot 16 = zeros (below wave 15)
    // botB[p][s][*]: slot s = BOTTOM row of wave s-1; slot 0 = zeros (above wave 0)
    __shared__ float topB[2][17][NY];
    __shared__ float botB[2][17][NY];

    // one-time init: sentinel zero rows + x prefetch
    {
        const int col = tid & 255;
        const int sel = tid >> 8;
        if      (sel == 0) topB[0][16][col] = 0.f;
        else if (sel == 1) topB[1][16][col] = 0.f;
        else if (sel == 2) botB[0][0][col]  = 0.f;
        else               botB[1][0][col]  = 0.f;
        if (tid < T_) xbuf[tid] = xin[b * T_ + tid];
    }

    // register-resident state + precombined coefficients
    float h1[16][4], h2[16][4], CA[16][4], CB[16][4], CC[16][4];
#pragma unroll
    for (int r = 0; r < 16; ++r) {
        const float4 cv = *reinterpret_cast<const float4*>(&cin[(x0 + r) * NY + y0]);
        const float4 bv = *reinterpret_cast<const float4*>(&bin[(x0 + r) * NY + y0]);
        const float cvv[4] = {cv.x, cv.y, cv.z, cv.w};
        const float bvv[4] = {bv.x, bv.y, bv.z, bv.w};
#pragma unroll
        for (int j = 0; j < 4; ++j) {
            const float c1  = 1.0f / (1.0f + 0.25f * bvv[j]);   // 0.5*DT = 0.25
            const float c2  = 1.0f - 0.25f * bvv[j];
            const float csq = 0.25f * cvv[j] * cvv[j];          // DT^2 * c^2
            CA[r][j] = c1 * (2.0f - 4.0f * csq);
            CB[r][j] = c1 * c2;
            CC[r][j] = c1 * csq;
            h1[r][j] = 0.f;
            h2[r][j] = 0.f;
        }
    }

    // source / probe ownership (sx,sy read as first 4 bytes: ok for i32 or i64)
    const int sx = sxp[0], sy = syp[0];
    const bool srcHere = (sx >= x0 && sx < x0 + 16 && sy >= y0 && sy < y0 + 4);
    const int  src_r = sx - x0, src_c = sy - y0;
    bool pHere[NP];
    int  pr[NP], pc[NP];
#pragma unroll
    for (int q = 0; q < NP; ++q) {
        const int pxx = pxp[q], pyy = pyp[q];
        pHere[q] = (pxx >= x0 && pxx < x0 + 16 && pyy >= y0 && pyy < y0 + 4);
        pr[q] = pxx - x0;
        pc[q] = pyy - y0;
    }

    __syncthreads();

    // one time step: reads H1 (field t), H2 (field t-1); writes new field into H2 in place.
    auto step = [&](float (&H1)[16][4], float (&H2)[16][4], int t, int p) {
        // stage my boundary rows
        *reinterpret_cast<float4*>(&topB[p][w][y0]) =
            make_float4(H1[0][0],  H1[0][1],  H1[0][2],  H1[0][3]);
        *reinterpret_cast<float4*>(&botB[p][w + 1][y0]) =
            make_float4(H1[15][0], H1[15][1], H1[15][2], H1[15][3]);
        __syncthreads();
        const float4 up = *reinterpret_cast<const float4*>(&botB[p][w][y0]);     // row x0-1
        const float4 dn = *reinterpret_cast<const float4*>(&topB[p][w + 1][y0]); // row x0+16
        const float upv[4] = {up.x, up.y, up.z, up.w};
        const float dnv[4] = {dn.x, dn.y, dn.z, dn.w};

#pragma unroll
        for (int r = 0; r < 16; ++r) {
            float lf = __shfl_up(H1[r][3], 1, 64);   // left neighbor of col 0
            float rt = __shfl_down(H1[r][0], 1, 64); // right neighbor of col 3
            if (l == 0)  lf = 0.f;
            if (l == 63) rt = 0.f;
#pragma unroll
            for (int j = 0; j < 4; ++j) {
                const float lv = (j == 0) ? lf  : H1[r][j - 1];
                const float rv = (j == 3) ? rt  : H1[r][j + 1];
                const float av = (r == 0)  ? upv[j] : H1[r - 1][j];
                const float dv = (r == 15) ? dnv[j] : H1[r + 1][j];
                const float s4 = (av + dv) + (lv + rv);
                float v = CA[r][j] * H1[r][j];
                v = fmaf(CC[r][j], s4, v);
                v = fmaf(-CB[r][j], H2[r][j], v);
                H2[r][j] = v;   // new field; safe: H2 only read at same cell
            }
        }
        // source injection (one thread; divergent tiny branch)
        if (srcHere) {
            const float xv = xbuf[t];
#pragma unroll
            for (int r = 0; r < 16; ++r)
#pragma unroll
                for (int j = 0; j < 4; ++j)
                    if (r == src_r && j == src_c) H2[r][j] += xv;
        }
        // probe readout (after source add)
#pragma unroll
        for (int q = 0; q < NP; ++q) {
            if (pHere[q]) {
                float v = 0.f;
#pragma unroll
                for (int r = 0; r < 16; ++r)
#pragma unroll
                    for (int j = 0; j < 4; ++j)
                        if (r == pr[q] && j == pc[q]) v = H2[r][j];
                out[(b * T_ + t) * NP + q] = v;
            }
        }
    };

    for (int t = 0; t < T_; t += 2) {
        step(h1, h2, t,     0);  // new field lands in h2
        step(h2, h1, t + 1, 1);  // new field lands in h1
    }
}

extern "C" void kernel_launch(void* const* d_in, const int* in_sizes, int n_in,
                              void* d_out, int out_size, void* d_ws, size_t ws_size,
                              hipStream_t stream)
{
    const float* x  = (const float*)d_in[0];
    const float* c  = (const float*)d_in[1];
    const float* bb = (const float*)d_in[2];
    const int*   px = (const int*)d_in[3];
    const int*   py = (const int*)d_in[4];
    const int*   sx = (const int*)d_in[5];
    const int*   sy = (const int*)d_in[6];
    float* out = (float*)d_out;

    wave_step_all<<<B_, 1024, 0, stream>>>(x, c, bb, px, py, sx, sy, out);
}

// Round 2
// 1628.012 us; speedup vs baseline: 4.3926x; 4.3926x over previous
//
#include <hip/hip_runtime.h>

// WaveRNN: damped 2D wave equation, B=16, T=256, 256x256 grid, 3 probes.
// 4 CUs per batch (64 WGs x 1024 threads). Each WG: one 64x256 slab, each
// thread a 4x4 cell tile in registers (~110 VGPR, fits 128 cap at 16 waves/CU).
// Intra-WG row halos: parity double-buffered LDS, one __syncthreads per step.
// Inter-WG halos: parity double-buffered global buffers + agent-scope
// release/acquire flags (neighbor-only handshake, no grid sync).

#define B_    16
#define T_    256
#define NX    256
#define NY    256
#define NP    3
#define NSLAB 4
#define WAVES 16
#define THREADS 1024
#define HALO_STRIDE (B_ * NSLAB * NY)   // floats per parity plane

__global__ void reset_ws(int* ws, int n)
{
    int i = blockIdx.x * blockDim.x + threadIdx.x;
    if (i < n) ws[i] = 0;
}

// One simulation step: reads H1 (field t) + H2 (field t-1), writes field t+1
// into H2 in place. All array indices compile-time constant (register promo).
#define STEP(H1, H2, TT) do { \
    const int p_ = (TT) & 1; \
    const int q_ = ((TT) + 1) & 1; \
    /* wait for neighbor slab halos of h^TT (t=0: flag>=0 trivially true) */ \
    if (w == 0 && s > 0) { \
        int* fp_ = &flagB[b * NSLAB + s - 1]; \
        while (__hip_atomic_load(fp_, __ATOMIC_ACQUIRE, __HIP_MEMORY_SCOPE_AGENT) < (TT)) {} \
    } \
    if (w == WAVES - 1 && s < NSLAB - 1) { \
        int* fp_ = &flagT[b * NSLAB + s + 1]; \
        while (__hip_atomic_load(fp_, __ATOMIC_ACQUIRE, __HIP_MEMORY_SCOPE_AGENT) < (TT)) {} \
    } \
    __syncthreads(); \
    float up_[4], dn_[4]; \
    if (w == 0) { \
        if (s > 0) { \
            float* hs_ = haloB + (size_t)p_ * HALO_STRIDE + (b * NSLAB + (s - 1)) * NY + y0; \
            _Pragma("unroll") for (int j = 0; j < 4; ++j) \
                up_[j] = __hip_atomic_load(hs_ + j, __ATOMIC_RELAXED, __HIP_MEMORY_SCOPE_AGENT); \
        } else { \
            _Pragma("unroll") for (int j = 0; j < 4; ++j) up_[j] = 0.f; \
        } \
    } else { \
        const float4 u4_ = *reinterpret_cast<const float4*>(&botL[p_][w - 1][y0]); \
        up_[0] = u4_.x; up_[1] = u4_.y; up_[2] = u4_.z; up_[3] = u4_.w; \
    } \
    if (w == WAVES - 1) { \
        if (s < NSLAB - 1) { \
            float* hs_ = haloT + (size_t)p_ * HALO_STRIDE + (b * NSLAB + (s + 1)) * NY + y0; \
            _Pragma("unroll") for (int j = 0; j < 4; ++j) \
                dn_[j] = __hip_atomic_load(hs_ + j, __ATOMIC_RELAXED, __HIP_MEMORY_SCOPE_AGENT); \
        } else { \
            _Pragma("unroll") for (int j = 0; j < 4; ++j) dn_[j] = 0.f; \
        } \
    } else { \
        const float4 d4_ = *reinterpret_cast<const float4*>(&topL[p_][w + 1][y0]); \
        dn_[0] = d4_.x; dn_[1] = d4_.y; dn_[2] = d4_.z; dn_[3] = d4_.w; \
    } \
    _Pragma("unroll") for (int r = 0; r < 4; ++r) { \
        float lf_ = __shfl_up(H1[r][3], 1, 64); \
        float rt_ = __shfl_down(H1[r][0], 1, 64); \
        if (l == 0)  lf_ = 0.f; \
        if (l == 63) rt_ = 0.f; \
        _Pragma("unroll") for (int j = 0; j < 4; ++j) { \
            const float lv_ = (j == 0) ? lf_ : H1[r][j - 1]; \
            const float rv_ = (j == 3) ? rt_ : H1[r][j + 1]; \
            const float av_ = (r == 0) ? up_[j] : H1[r - 1][j]; \
            const float dv_ = (r == 3) ? dn_[j] : H1[r + 1][j]; \
            const float s4_ = (av_ + dv_) + (lv_ + rv_); \
            float v_ = CA[r][j] * H1[r][j]; \
            v_ = fmaf(CC[r][j], s4_, v_); \
            v_ = fmaf(-CB[r][j], H2[r][j], v_); \
            H2[r][j] = v_; \
        } \
    } \
    if (srcHere) { \
        const float xv_ = xbuf[TT]; \
        _Pragma("unroll") for (int r = 0; r < 4; ++r) \
            _Pragma("unroll") for (int j = 0; j < 4; ++j) \
                if (r == src_r && j == src_c) H2[r][j] += xv_; \
    } \
    _Pragma("unroll") for (int qq = 0; qq < NP; ++qq) { \
        if (pHere[qq]) { \
            float v_ = 0.f; \
            _Pragma("unroll") for (int r = 0; r < 4; ++r) \
                _Pragma("unroll") for (int j = 0; j < 4; ++j) \
                    if (r == pr[qq] && j == pc[qq]) v_ = H2[r][j]; \
            out[((size_t)b * T_ + (TT)) * NP + qq] = v_; \
        } \
    } \
    /* stage new-field boundary rows for step TT+1 (parity q_) */ \
    *reinterpret_cast<float4*>(&topL[q_][w][y0]) = make_float4(H2[0][0], H2[0][1], H2[0][2], H2[0][3]); \
    *reinterpret_cast<float4*>(&botL[q_][w][y0]) = make_float4(H2[3][0], H2[3][1], H2[3][2], H2[3][3]); \
    if (w == 0 && s > 0) { \
        float* hd_ = haloT + (size_t)q_ * HALO_STRIDE + (b * NSLAB + s) * NY + y0; \
        _Pragma("unroll") for (int j = 0; j < 4; ++j) \
            __hip_atomic_store(hd_ + j, H2[0][j], __ATOMIC_RELAXED, __HIP_MEMORY_SCOPE_AGENT); \
        if (l == 0) { \
            __threadfence(); \
            __hip_atomic_store(&flagT[b * NSLAB + s], (TT) + 1, __ATOMIC_RELEASE, __HIP_MEMORY_SCOPE_AGENT); \
        } \
    } \
    if (w == WAVES - 1 && s < NSLAB - 1) { \
        float* hd_ = haloB + (size_t)q_ * HALO_STRIDE + (b * NSLAB + s) * NY + y0; \
        _Pragma("unroll") for (int j = 0; j < 4; ++j) \
            __hip_atomic_store(hd_ + j, H2[3][j], __ATOMIC_RELAXED, __HIP_MEMORY_SCOPE_AGENT); \
        if (l == 0) { \
            __threadfence(); \
            __hip_atomic_store(&flagB[b * NSLAB + s], (TT) + 1, __ATOMIC_RELEASE, __HIP_MEMORY_SCOPE_AGENT); \
        } \
    } \
} while (0)

__launch_bounds__(THREADS, 4)
__global__ void wave_multi(const float* __restrict__ xin,
                           const float* __restrict__ cin,
                           const float* __restrict__ bin,
                           const int* __restrict__ pxp,
                           const int* __restrict__ pyp,
                           const int* __restrict__ sxp,
                           const int* __restrict__ syp,
                           float* __restrict__ out,
                           float* __restrict__ haloT,   // [2][B_][NSLAB][NY]
                           float* __restrict__ haloB,   // [2][B_][NSLAB][NY]
                           int* __restrict__ flagT,     // [B_][NSLAB]
                           int* __restrict__ flagB)     // [B_][NSLAB]
{
    const int blk = blockIdx.x;
    const int b = blk >> 2;           // batch
    const int s = blk & 3;            // slab: rows [s*64, s*64+64)
    const int tid = threadIdx.x;
    const int w = tid >> 6;           // wave 0..15 -> rows s*64 + w*4 .. +3
    const int l = tid & 63;           // lane -> cols l*4 .. +3
    const int r0 = s * 64 + w * 4;    // global row of tile row 0
    const int y0 = l * 4;             // global col of tile col 0

    __shared__ float xbuf[T_];
    __shared__ float topL[2][WAVES][NY];   // [parity][wave] = tile row 0
    __shared__ float botL[2][WAVES][NY];   // [parity][wave] = tile row 3

    // zero parity-0 LDS halos (h^0 = 0); xbuf prefetch
    for (int i = tid; i < WAVES * NY; i += THREADS) {
        (&topL[0][0][0])[i] = 0.f;
        (&botL[0][0][0])[i] = 0.f;
    }
    if (tid < T_) xbuf[tid] = xin[b * T_ + tid];

    // register state + precombined coefficients
    float h1[4][4], h2[4][4], CA[4][4], CB[4][4], CC[4][4];
#pragma unroll
    for (int r = 0; r < 4; ++r) {
        const float4 cv = *reinterpret_cast<const float4*>(&cin[(r0 + r) * NY + y0]);
        const float4 bv = *reinterpret_cast<const float4*>(&bin[(r0 + r) * NY + y0]);
        const float cvv[4] = {cv.x, cv.y, cv.z, cv.w};
        const float bvv[4] = {bv.x, bv.y, bv.z, bv.w};
#pragma unroll
        for (int j = 0; j < 4; ++j) {
            const float c1  = 1.0f / (1.0f + 0.25f * bvv[j]);   // 0.5*DT = 0.25
            const float c2  = 1.0f - 0.25f * bvv[j];
            const float csq = 0.25f * cvv[j] * cvv[j];          // DT^2 * c^2
            CA[r][j] = c1 * (2.0f - 4.0f * csq);
            CB[r][j] = c1 * c2;
            CC[r][j] = c1 * csq;
            h1[r][j] = 0.f;
            h2[r][j] = 0.f;
        }
    }

    const int sx = sxp[0], sy = syp[0];
    const bool srcHere = (sx >= r0 && sx < r0 + 4 && sy >= y0 && sy < y0 + 4);
    const int  src_r = sx - r0, src_c = sy - y0;
    bool pHere[NP];
    int  pr[NP], pc[NP];
#pragma unroll
    for (int q = 0; q < NP; ++q) {
        const int pxx = pxp[q], pyy = pyp[q];
        pHere[q] = (pxx >= r0 && pxx < r0 + 4 && pyy >= y0 && pyy < y0 + 4);
        pr[q] = pxx - r0;
        pc[q] = pyy - y0;
    }

#pragma unroll 1
    for (int t = 0; t < T_; t += 2) {
        STEP(h1, h2, t);        // h^{t+1} lands in h2
        STEP(h2, h1, t + 1);    // h^{t+2} lands in h1
    }
}

extern "C" void kernel_launch(void* const* d_in, const int* in_sizes, int n_in,
                              void* d_out, int out_size, void* d_ws, size_t ws_size,
                              hipStream_t stream)
{
    const float* x  = (const float*)d_in[0];
    const float* c  = (const float*)d_in[1];
    const float* bb = (const float*)d_in[2];
    const int*   px = (const int*)d_in[3];
    const int*   py = (const int*)d_in[4];
    const int*   sx = (const int*)d_in[5];
    const int*   sy = (const int*)d_in[6];
    float* out = (float*)d_out;

    float* haloT = (float*)d_ws;                       // [2][16][4][256]
    float* haloB = haloT + 2 * HALO_STRIDE;            // [2][16][4][256]
    int*   flagT = (int*)(haloB + 2 * HALO_STRIDE);    // [16][4]
    int*   flagB = flagT + B_ * NSLAB;                 // [16][4]

    const int words = 2 * HALO_STRIDE * 2 + 2 * B_ * NSLAB;  // 65664
    reset_ws<<<(words + 255) / 256, 256, 0, stream>>>((int*)d_ws, words);

    void* args[] = { (void*)&x, (void*)&c, (void*)&bb, (void*)&px, (void*)&py,
                     (void*)&sx, (void*)&sy, (void*)&out, (void*)&haloT,
                     (void*)&haloB, (void*)&flagT, (void*)&flagB };
    hipLaunchCooperativeKernel(reinterpret_cast<void*>(wave_multi),
                               dim3(B_ * NSLAB), dim3(THREADS), args, 0, stream);
}

// Round 3
// 468.248 us; speedup vs baseline: 15.2724x; 3.4768x over previous
//
#include <hip/hip_runtime.h>

// WaveRNN: damped 2D wave equation, B=16, T=256, 256x256 grid, 3 probes.
// 8 slabs per batch (128 WGs x 512 threads, cooperative). Each WG: one 32x256
// slab; each thread a 4x4 register tile (~100 VGPR, cap 256 at 8 waves/WG).
// Intra-WG row halos: parity double-buffered LDS + one __syncthreads/step.
// Inter-WG halos: tagged 8-byte packets {step, value} in device-global memory,
// relaxed agent-scope atomics, parity double-buffered. No fences, no flags:
// each packet is self-describing (single-copy atomic), so a consumer just
// polls its own 4 packets until tag==t.

#define B_    16
#define T_    256
#define NX    256
#define NY    256
#define NP    3
#define NSLAB 8
#define WAVES 8
#define THREADS 512
#define NIF   (NSLAB - 1)    // interfaces per batch

// [batch][iface][parity][col]
__device__ uint64_t g_haloDn[B_][NIF][2][NY];  // upper slab's bottom row
__device__ uint64_t g_haloUp[B_][NIF][2][NY];  // lower slab's top row

__global__ void reset_halo()
{
    const int n = B_ * NIF * 2 * NY;
    int i = blockIdx.x * blockDim.x + threadIdx.x;
    if (i < n) {
        (&g_haloDn[0][0][0][0])[i] = 0ull;
        (&g_haloUp[0][0][0][0])[i] = 0ull;
    }
}

#define PACK(tag, f) (((uint64_t)(uint32_t)(tag) << 32) | (uint64_t)__float_as_uint(f))

// One step: reads H1 (field t) + H2 (field t-1), writes field t+1 into H2.
#define STEP(H1, H2, TT) do { \
    const int p_ = (TT) & 1; \
    const int q_ = ((TT) + 1) & 1; \
    float up_[4], dn_[4]; \
    /* inter-WG ghosts: poll own tagged packets (before the barrier) */ \
    if (w == 0 && s > 0) { \
        uint64_t* gp_ = &g_haloDn[b][s - 1][p_][y0]; \
        uint64_t v0_, v1_, v2_, v3_; \
        for (;;) { \
            v0_ = __hip_atomic_load(gp_ + 0, __ATOMIC_RELAXED, __HIP_MEMORY_SCOPE_AGENT); \
            v1_ = __hip_atomic_load(gp_ + 1, __ATOMIC_RELAXED, __HIP_MEMORY_SCOPE_AGENT); \
            v2_ = __hip_atomic_load(gp_ + 2, __ATOMIC_RELAXED, __HIP_MEMORY_SCOPE_AGENT); \
            v3_ = __hip_atomic_load(gp_ + 3, __ATOMIC_RELAXED, __HIP_MEMORY_SCOPE_AGENT); \
            if ((uint32_t)(v0_ >> 32) == (uint32_t)(TT) && \
                (uint32_t)(v1_ >> 32) == (uint32_t)(TT) && \
                (uint32_t)(v2_ >> 32) == (uint32_t)(TT) && \
                (uint32_t)(v3_ >> 32) == (uint32_t)(TT)) break; \
        } \
        up_[0] = __uint_as_float((uint32_t)v0_); \
        up_[1] = __uint_as_float((uint32_t)v1_); \
        up_[2] = __uint_as_float((uint32_t)v2_); \
        up_[3] = __uint_as_float((uint32_t)v3_); \
    } \
    if (w == WAVES - 1 && s < NSLAB - 1) { \
        uint64_t* gp_ = &g_haloUp[b][s][p_][y0]; \
        uint64_t v0_, v1_, v2_, v3_; \
        for (;;) { \
            v0_ = __hip_atomic_load(gp_ + 0, __ATOMIC_RELAXED, __HIP_MEMORY_SCOPE_AGENT); \
            v1_ = __hip_atomic_load(gp_ + 1, __ATOMIC_RELAXED, __HIP_MEMORY_SCOPE_AGENT); \
            v2_ = __hip_atomic_load(gp_ + 2, __ATOMIC_RELAXED, __HIP_MEMORY_SCOPE_AGENT); \
            v3_ = __hip_atomic_load(gp_ + 3, __ATOMIC_RELAXED, __HIP_MEMORY_SCOPE_AGENT); \
            if ((uint32_t)(v0_ >> 32) == (uint32_t)(TT) && \
                (uint32_t)(v1_ >> 32) == (uint32_t)(TT) && \
                (uint32_t)(v2_ >> 32) == (uint32_t)(TT) && \
                (uint32_t)(v3_ >> 32) == (uint32_t)(TT)) break; \
        } \
        dn_[0] = __uint_as_float((uint32_t)v0_); \
        dn_[1] = __uint_as_float((uint32_t)v1_); \
        dn_[2] = __uint_as_float((uint32_t)v2_); \
        dn_[3] = __uint_as_float((uint32_t)v3_); \
    } \
    __syncthreads(); \
    if (w == 0) { \
        if (s == 0) { _Pragma("unroll") for (int j = 0; j < 4; ++j) up_[j] = 0.f; } \
    } else { \
        const float4 u4_ = *reinterpret_cast<const float4*>(&botL[p_][w - 1][y0]); \
        up_[0] = u4_.x; up_[1] = u4_.y; up_[2] = u4_.z; up_[3] = u4_.w; \
    } \
    if (w == WAVES - 1) { \
        if (s == NSLAB - 1) { _Pragma("unroll") for (int j = 0; j < 4; ++j) dn_[j] = 0.f; } \
    } else { \
        const float4 d4_ = *reinterpret_cast<const float4*>(&topL[p_][w + 1][y0]); \
        dn_[0] = d4_.x; dn_[1] = d4_.y; dn_[2] = d4_.z; dn_[3] = d4_.w; \
    } \
    _Pragma("unroll") for (int r = 0; r < 4; ++r) { \
        float lf_ = __shfl_up(H1[r][3], 1, 64); \
        float rt_ = __shfl_down(H1[r][0], 1, 64); \
        if (l == 0)  lf_ = 0.f; \
        if (l == 63) rt_ = 0.f; \
        _Pragma("unroll") for (int j = 0; j < 4; ++j) { \
            const float lv_ = (j == 0) ? lf_ : H1[r][j - 1]; \
            const float rv_ = (j == 3) ? rt_ : H1[r][j + 1]; \
            const float av_ = (r == 0) ? up_[j] : H1[r - 1][j]; \
            const float dv_ = (r == 3) ? dn_[j] : H1[r + 1][j]; \
            const float s4_ = (av_ + dv_) + (lv_ + rv_); \
            const float d_  = H1[r][j] - H2[r][j]; \
            const float e_  = fmaf(-4.0f, H1[r][j], s4_); \
            float v_ = fmaf(CC[r][j], e_, H2[r][j]); \
            v_ = fmaf(TC[r][j], d_, v_); \
            H2[r][j] = v_; \
        } \
    } \
    if (srcHere) { \
        const float xv_ = xbuf[TT]; \
        _Pragma("unroll") for (int r = 0; r < 4; ++r) \
            _Pragma("unroll") for (int j = 0; j < 4; ++j) \
                if (r == src_r && j == src_c) H2[r][j] += xv_; \
    } \
    _Pragma("unroll") for (int qq = 0; qq < NP; ++qq) { \
        if (pHere[qq]) { \
            float v_ = 0.f; \
            _Pragma("unroll") for (int r = 0; r < 4; ++r) \
                _Pragma("unroll") for (int j = 0; j < 4; ++j) \
                    if (r == pr[qq] && j == pc[qq]) v_ = H2[r][j]; \
            out[((size_t)b * T_ + (TT)) * NP + qq] = v_; \
        } \
    } \
    /* stage new-field boundary rows for step TT+1 */ \
    *reinterpret_cast<float4*>(&topL[q_][w][y0]) = make_float4(H2[0][0], H2[0][1], H2[0][2], H2[0][3]); \
    *reinterpret_cast<float4*>(&botL[q_][w][y0]) = make_float4(H2[3][0], H2[3][1], H2[3][2], H2[3][3]); \
    if (w == 0 && s > 0) { \
        uint64_t* hd_ = &g_haloUp[b][s - 1][q_][y0]; \
        _Pragma("unroll") for (int j = 0; j < 4; ++j) \
            __hip_atomic_store(hd_ + j, PACK((TT) + 1, H2[0][j]), __ATOMIC_RELAXED, __HIP_MEMORY_SCOPE_AGENT); \
    } \
    if (w == WAVES - 1 && s < NSLAB - 1) { \
        uint64_t* hd_ = &g_haloDn[b][s][q_][y0]; \
        _Pragma("unroll") for (int j = 0; j < 4; ++j) \
            __hip_atomic_store(hd_ + j, PACK((TT) + 1, H2[3][j]), __ATOMIC_RELAXED, __HIP_MEMORY_SCOPE_AGENT); \
    } \
} while (0)

__launch_bounds__(THREADS, 2)
__global__ void wave_multi(const float* __restrict__ xin,
                           const float* __restrict__ cin,
                           const float* __restrict__ bin,
                           const int* __restrict__ pxp,
                           const int* __restrict__ pyp,
                           const int* __restrict__ sxp,
                           const int* __restrict__ syp,
                           float* __restrict__ out)
{
    const int blk = blockIdx.x;
    const int b = blk >> 3;           // batch
    const int s = blk & 7;            // slab: rows [s*32, s*32+32)
    const int tid = threadIdx.x;
    const int w = tid >> 6;           // wave 0..7 -> rows s*32 + w*4 .. +3
    const int l = tid & 63;           // lane -> cols l*4 .. +3
    const int r0 = s * 32 + w * 4;    // global row of tile row 0
    const int y0 = l * 4;             // global col of tile col 0

    __shared__ float xbuf[T_];
    __shared__ float topL[2][WAVES][NY];   // [parity][wave] = tile row 0
    __shared__ float botL[2][WAVES][NY];   // [parity][wave] = tile row 3

    for (int i = tid; i < WAVES * NY; i += THREADS) {
        (&topL[0][0][0])[i] = 0.f;
        (&botL[0][0][0])[i] = 0.f;
    }
    if (tid < T_) xbuf[tid] = xin[b * T_ + tid];

    // register state + compressed coefficients: TC = 2*c1, CC = c1*(DT^2*c^2).
    // hn = h2 + TC*(h1-h2) + CC*(s4 - 4*h1)   [uses c1*c2 == 2*c1 - 1]
    float h1[4][4], h2[4][4], TC[4][4], CC[4][4];
#pragma unroll
    for (int r = 0; r < 4; ++r) {
        const float4 cv = *reinterpret_cast<const float4*>(&cin[(r0 + r) * NY + y0]);
        const float4 bv = *reinterpret_cast<const float4*>(&bin[(r0 + r) * NY + y0]);
        const float cvv[4] = {cv.x, cv.y, cv.z, cv.w};
        const float bvv[4] = {bv.x, bv.y, bv.z, bv.w};
#pragma unroll
        for (int j = 0; j < 4; ++j) {
            const float c1  = 1.0f / (1.0f + 0.25f * bvv[j]);   // 0.5*DT = 0.25
            const float csq = 0.25f * cvv[j] * cvv[j];          // DT^2 * c^2
            TC[r][j] = 2.0f * c1;
            CC[r][j] = c1 * csq;
            h1[r][j] = 0.f;
            h2[r][j] = 0.f;
        }
    }

    const int sx = sxp[0], sy = syp[0];
    const bool srcHere = (sx >= r0 && sx < r0 + 4 && sy >= y0 && sy < y0 + 4);
    const int  src_r = sx - r0, src_c = sy - y0;
    bool pHere[NP];
    int  pr[NP], pc[NP];
#pragma unroll
    for (int q = 0; q < NP; ++q) {
        const int pxx = pxp[q], pyy = pyp[q];
        pHere[q] = (pxx >= r0 && pxx < r0 + 4 && pyy >= y0 && pyy < y0 + 4);
        pr[q] = pxx - r0;
        pc[q] = pyy - y0;
    }

#pragma unroll 1
    for (int t = 0; t < T_; t += 2) {
        STEP(h1, h2, t);        // h^{t+1} lands in h2
        STEP(h2, h1, t + 1);    // h^{t+2} lands in h1
    }
}

extern "C" void kernel_launch(void* const* d_in, const int* in_sizes, int n_in,
                              void* d_out, int out_size, void* d_ws, size_t ws_size,
                              hipStream_t stream)
{
    const float* x  = (const float*)d_in[0];
    const float* c  = (const float*)d_in[1];
    const float* bb = (const float*)d_in[2];
    const int*   px = (const int*)d_in[3];
    const int*   py = (const int*)d_in[4];
    const int*   sx = (const int*)d_in[5];
    const int*   sy = (const int*)d_in[6];
    float* out = (float*)d_out;

    const int words = B_ * NIF * 2 * NY;   // u64 elements per halo array
    reset_halo<<<(words + 255) / 256, 256, 0, stream>>>();

    void* args[] = { (void*)&x, (void*)&c, (void*)&bb, (void*)&px, (void*)&py,
                     (void*)&sx, (void*)&sy, (void*)&out };
    hipLaunchCooperativeKernel(reinterpret_cast<void*>(wave_multi),
                               dim3(B_ * NSLAB), dim3(THREADS), args, 0, stream);
}

// Round 4
// 428.029 us; speedup vs baseline: 16.7075x; 1.0940x over previous
//
#include <hip/hip_runtime.h>

// WaveRNN: damped 2D wave equation, B=16, T=256, 256x256 grid, 3 probes.
// 8 slabs per batch (128 WGs x 512 threads, cooperative). Each WG: one 32x256
// slab; each thread a 4x4 register tile. Temporal blocking K=4: slab-boundary
// waves keep 4 ghost rows (both time levels) in registers and redundantly
// step them (trapezoid), so inter-slab exchange happens every 4 steps only.
// Exchange = tagged 8-byte packets {chunk, value}, relaxed agent-scope
// atomics, parity double-buffered, coalesced packed layout. No fences/flags.
// Intra-WG row halos: parity double-buffered LDS + one __syncthreads/substep.

#define B_    16
#define T_    256
#define NY    256
#define NP    3
#define NSLAB 8
#define WAVES 8
#define THREADS 512
#define NIF   (NSLAB - 1)
#define KCH   4
#define NCHUNK (T_ / KCH)

// [batch][iface][side][parity][rowfield(0..3:h1 rows,4..7:h2 rows)][packed col]
// side 0: upper slab's bottom 4 rows (lower slab's up-ghosts)
// side 1: lower slab's top 4 rows   (upper slab's down-ghosts)
// packed col index = (col&3)*64 + (col>>2) -> per-instruction contiguous 512B
__device__ uint64_t g_halo[B_][NIF][2][2][8][NY];

__global__ void reset_halo()
{
    const int n = B_ * NIF * 2 * 2 * 8 * NY;
    int i = blockIdx.x * blockDim.x + threadIdx.x;
    if (i < n) (&g_halo[0][0][0][0][0][0])[i] = 0ull;
}

#define PACK(tag, f) (((uint64_t)(uint32_t)(tag) << 32) | (uint64_t)__float_as_uint(f))

// One substep: H1 = h^t, H2 = h^{t-1} -> new field h^{t+1} written into H2.
// Ghosts: GA = ghost h^t, GB = ghost h^{t-1} -> valid ghost rows updated into GB.
// K_ is the substep index within the chunk (compile-time 0..3).
#define SUB(H1, H2, GA, GB, K_, TT) do { \
    __syncthreads(); \
    const int p_ = (K_) & 1; \
    const int q_ = ((K_) + 1) & 1; \
    float up_[4], dn_[4]; \
    if (w == 0) { \
        if (s == 0) { _Pragma("unroll") for (int j = 0; j < 4; ++j) up_[j] = 0.f; } \
        else        { _Pragma("unroll") for (int j = 0; j < 4; ++j) up_[j] = GA[3][j]; } \
    } else { \
        const float4 u4_ = *reinterpret_cast<const float4*>(&botL[p_][w - 1][y0]); \
        up_[0] = u4_.x; up_[1] = u4_.y; up_[2] = u4_.z; up_[3] = u4_.w; \
    } \
    if (w == WAVES - 1) { \
        if (s == NSLAB - 1) { _Pragma("unroll") for (int j = 0; j < 4; ++j) dn_[j] = 0.f; } \
        else                { _Pragma("unroll") for (int j = 0; j < 4; ++j) dn_[j] = GA[0][j]; } \
    } else { \
        const float4 d4_ = *reinterpret_cast<const float4*>(&topL[p_][w + 1][y0]); \
        dn_[0] = d4_.x; dn_[1] = d4_.y; dn_[2] = d4_.z; dn_[3] = d4_.w; \
    } \
    /* owned rows */ \
    _Pragma("unroll") for (int r = 0; r < 4; ++r) { \
        float lf_ = __shfl_up(H1[r][3], 1, 64); \
        float rt_ = __shfl_down(H1[r][0], 1, 64); \
        if (l == 0)  lf_ = 0.f; \
        if (l == 63) rt_ = 0.f; \
        _Pragma("unroll") for (int j = 0; j < 4; ++j) { \
            const float lv_ = (j == 0) ? lf_ : H1[r][j - 1]; \
            const float rv_ = (j == 3) ? rt_ : H1[r][j + 1]; \
            const float av_ = (r == 0) ? up_[j] : H1[r - 1][j]; \
            const float dv_ = (r == 3) ? dn_[j] : H1[r + 1][j]; \
            const float s4_ = (av_ + dv_) + (lv_ + rv_); \
            const float d_  = H1[r][j] - H2[r][j]; \
            const float e_  = fmaf(-4.0f, H1[r][j], s4_); \
            float v_ = fmaf(CC[r][j], e_, H2[r][j]); \
            v_ = fmaf(TC[r][j], d_, v_); \
            H2[r][j] = v_; \
        } \
    } \
    /* ghost rows (trapezoid, shrinking validity) */ \
    if (upG) { \
        _Pragma("unroll") for (int i = 1; i < 4; ++i) { \
            if (i >= (K_) + 1) { \
                float lf_ = __shfl_up(GA[i][3], 1, 64); \
                float rt_ = __shfl_down(GA[i][0], 1, 64); \
                if (l == 0)  lf_ = 0.f; \
                if (l == 63) rt_ = 0.f; \
                _Pragma("unroll") for (int j = 0; j < 4; ++j) { \
                    const float lv_ = (j == 0) ? lf_ : GA[i][j - 1]; \
                    const float rv_ = (j == 3) ? rt_ : GA[i][j + 1]; \
                    const float av_ = GA[i - 1][j]; \
                    const float dv_ = (i == 3) ? H1[0][j] : GA[i + 1][j]; \
                    const float s4_ = (av_ + dv_) + (lv_ + rv_); \
                    const float d_  = GA[i][j] - GB[i][j]; \
                    const float e_  = fmaf(-4.0f, GA[i][j], s4_); \
                    float v_ = fmaf(gCC[i][j], e_, GB[i][j]); \
                    v_ = fmaf(gTC[i][j], d_, v_); \
                    if (gsrcHere && i == gsrc_r && j == gsrc_c) v_ += xbuf[TT]; \
                    GB[i][j] = v_; \
                } \
            } \
        } \
    } \
    if (dnG) { \
        _Pragma("unroll") for (int i = 0; i < 3; ++i) { \
            if (i <= 2 - (K_)) { \
                float lf_ = __shfl_up(GA[i][3], 1, 64); \
                float rt_ = __shfl_down(GA[i][0], 1, 64); \
                if (l == 0)  lf_ = 0.f; \
                if (l == 63) rt_ = 0.f; \
                _Pragma("unroll") for (int j = 0; j < 4; ++j) { \
                    const float lv_ = (j == 0) ? lf_ : GA[i][j - 1]; \
                    const float rv_ = (j == 3) ? rt_ : GA[i][j + 1]; \
                    const float av_ = (i == 0) ? H1[3][j] : GA[i - 1][j]; \
                    const float dv_ = GA[i + 1][j]; \
                    const float s4_ = (av_ + dv_) + (lv_ + rv_); \
                    const float d_  = GA[i][j] - GB[i][j]; \
                    const float e_  = fmaf(-4.0f, GA[i][j], s4_); \
                    float v_ = fmaf(gCC[i][j], e_, GB[i][j]); \
                    v_ = fmaf(gTC[i][j], d_, v_); \
                    if (gsrcHere && i == gsrc_r && j == gsrc_c) v_ += xbuf[TT]; \
                    GB[i][j] = v_; \
                } \
            } \
        } \
    } \
    /* source into owned */ \
    if (srcHere) { \
        const float xv_ = xbuf[TT]; \
        _Pragma("unroll") for (int r = 0; r < 4; ++r) \
            _Pragma("unroll") for (int j = 0; j < 4; ++j) \
                if (r == src_r && j == src_c) H2[r][j] += xv_; \
    } \
    /* probes (owned cells only) */ \
    _Pragma("unroll") for (int qq = 0; qq < NP; ++qq) { \
        if (pHere[qq]) { \
            float v_ = 0.f; \
            _Pragma("unroll") for (int r = 0; r < 4; ++r) \
                _Pragma("unroll") for (int j = 0; j < 4; ++j) \
                    if (r == pr[qq] && j == pc[qq]) v_ = H2[r][j]; \
            out[((size_t)b * T_ + (TT)) * NP + qq] = v_; \
        } \
    } \
    /* stage new-field boundary rows for next substep */ \
    *reinterpret_cast<float4*>(&topL[q_][w][y0]) = make_float4(H2[0][0], H2[0][1], H2[0][2], H2[0][3]); \
    *reinterpret_cast<float4*>(&botL[q_][w][y0]) = make_float4(H2[3][0], H2[3][1], H2[3][2], H2[3][3]); \
} while (0)

__launch_bounds__(THREADS, 1)
__global__ void wave_multi(const float* __restrict__ xin,
                           const float* __restrict__ cin,
                           const float* __restrict__ bin,
                           const int* __restrict__ pxp,
                           const int* __restrict__ pyp,
                           const int* __restrict__ sxp,
                           const int* __restrict__ syp,
                           float* __restrict__ out)
{
    const int blk = blockIdx.x;
    const int b = blk >> 3;           // batch
    const int s = blk & 7;            // slab: rows [s*32, s*32+32)
    const int tid = threadIdx.x;
    const int w = tid >> 6;           // wave 0..7 -> rows s*32 + w*4 .. +3
    const int l = tid & 63;           // lane -> cols l*4 .. +3
    const int r0 = s * 32 + w * 4;
    const int y0 = l * 4;

    __shared__ float xbuf[T_];
    __shared__ float topL[2][WAVES][NY];   // [parity][wave] = tile row 0
    __shared__ float botL[2][WAVES][NY];   // [parity][wave] = tile row 3

    for (int i = tid; i < WAVES * NY; i += THREADS) {
        (&topL[0][0][0])[i] = 0.f;
        (&botL[0][0][0])[i] = 0.f;
    }
    if (tid < T_) xbuf[tid] = xin[b * T_ + tid];

    // owned state + compressed coefficients: TC = 2*c1, CC = c1*(DT^2*c^2)
    // hn = h2 + TC*(h1-h2) + CC*(s4 - 4*h1)   [c1*c2 == 2*c1 - 1]
    float h1[4][4], h2[4][4], TC[4][4], CC[4][4];
#pragma unroll
    for (int r = 0; r < 4; ++r) {
        const float4 cv = *reinterpret_cast<const float4*>(&cin[(r0 + r) * NY + y0]);
        const float4 bv = *reinterpret_cast<const float4*>(&bin[(r0 + r) * NY + y0]);
        const float cvv[4] = {cv.x, cv.y, cv.z, cv.w};
        const float bvv[4] = {bv.x, bv.y, bv.z, bv.w};
#pragma unroll
        for (int j = 0; j < 4; ++j) {
            const float c1  = 1.0f / (1.0f + 0.25f * bvv[j]);
            const float csq = 0.25f * cvv[j] * cvv[j];
            TC[r][j] = 2.0f * c1;
            CC[r][j] = c1 * csq;
            h1[r][j] = 0.f;
            h2[r][j] = 0.f;
        }
    }

    // ghost setup
    const bool upG = (w == 0 && s > 0);
    const bool dnG = (w == WAVES - 1 && s < NSLAB - 1);
    const int gr0 = upG ? (r0 - 4) : (dnG ? (r0 + 4) : r0);  // ghost rows gr0..gr0+3
    float ga[4][4], gb[4][4], gTC[4][4], gCC[4][4];
#pragma unroll
    for (int i = 0; i < 4; ++i) {
        const float4 cv = *reinterpret_cast<const float4*>(&cin[(gr0 + i) * NY + y0]);
        const float4 bv = *reinterpret_cast<const float4*>(&bin[(gr0 + i) * NY + y0]);
        const float cvv[4] = {cv.x, cv.y, cv.z, cv.w};
        const float bvv[4] = {bv.x, bv.y, bv.z, bv.w};
#pragma unroll
        for (int j = 0; j < 4; ++j) {
            const float c1  = 1.0f / (1.0f + 0.25f * bvv[j]);
            const float csq = 0.25f * cvv[j] * cvv[j];
            gTC[i][j] = 2.0f * c1;
            gCC[i][j] = c1 * csq;
            ga[i][j] = 0.f;
            gb[i][j] = 0.f;
        }
    }

    const int sx = sxp[0], sy = syp[0];
    const bool srcHere = (sx >= r0 && sx < r0 + 4 && sy >= y0 && sy < y0 + 4);
    const int  src_r = sx - r0, src_c = sy - y0;
    const bool gsrcHere = (upG || dnG) && (sx >= gr0 && sx < gr0 + 4 && sy >= y0 && sy < y0 + 4);
    const int  gsrc_r = sx - gr0, gsrc_c = sy - y0;
    bool pHere[NP];
    int  pr[NP], pc[NP];
#pragma unroll
    for (int q = 0; q < NP; ++q) {
        const int pxx = pxp[q], pyy = pyp[q];
        pHere[q] = (pxx >= r0 && pxx < r0 + 4 && pyy >= y0 && pyy < y0 + 4);
        pr[q] = pxx - r0;
        pc[q] = pyy - y0;
    }

#pragma unroll 1
    for (int c = 0; c < NCHUNK; ++c) {
        // receive ghosts for this chunk (h1 = h^{4c}, h2 = h^{4c-1}); c=0: zeros
        if ((c > 0) && (upG || dnG)) {
            const int iface = upG ? (s - 1) : s;
            const int side  = upG ? 0 : 1;
            uint64_t* gp = &g_halo[b][iface][side][c & 1][0][0];
            uint64_t vv[8][4];
            bool ok;
            do {
                ok = true;
#pragma unroll
                for (int rf = 0; rf < 8; ++rf)
#pragma unroll
                    for (int j = 0; j < 4; ++j)
                        vv[rf][j] = __hip_atomic_load(gp + rf * NY + j * 64 + l,
                                                      __ATOMIC_RELAXED, __HIP_MEMORY_SCOPE_AGENT);
#pragma unroll
                for (int rf = 0; rf < 8; ++rf)
#pragma unroll
                    for (int j = 0; j < 4; ++j)
                        ok = ok && ((uint32_t)(vv[rf][j] >> 32) == (uint32_t)c);
            } while (!ok);
#pragma unroll
            for (int i = 0; i < 4; ++i)
#pragma unroll
                for (int j = 0; j < 4; ++j) {
                    ga[i][j] = __uint_as_float((uint32_t)vv[i][j]);
                    gb[i][j] = __uint_as_float((uint32_t)vv[4 + i][j]);
                }
        }

        SUB(h1, h2, ga, gb, 0, 4 * c + 0);
        SUB(h2, h1, gb, ga, 1, 4 * c + 1);
        SUB(h1, h2, ga, gb, 2, 4 * c + 2);
        SUB(h2, h1, gb, ga, 3, 4 * c + 3);
        // now h1 = h^{4c+4}, h2 = h^{4c+3}

        // publish boundary rows for neighbors' next chunk
        if ((c + 1 < NCHUNK) && (upG || dnG)) {
            const int iface = upG ? (s - 1) : s;
            const int side  = upG ? 1 : 0;
            uint64_t* gp = &g_halo[b][iface][side][(c + 1) & 1][0][0];
#pragma unroll
            for (int i = 0; i < 4; ++i)
#pragma unroll
                for (int j = 0; j < 4; ++j) {
                    __hip_atomic_store(gp + i * NY + j * 64 + l, PACK(c + 1, h1[i][j]),
                                       __ATOMIC_RELAXED, __HIP_MEMORY_SCOPE_AGENT);
                    __hip_atomic_store(gp + (4 + i) * NY + j * 64 + l, PACK(c + 1, h2[i][j]),
                                       __ATOMIC_RELAXED, __HIP_MEMORY_SCOPE_AGENT);
                }
        }
    }
}

extern "C" void kernel_launch(void* const* d_in, const int* in_sizes, int n_in,
                              void* d_out, int out_size, void* d_ws, size_t ws_size,
                              hipStream_t stream)
{
    const float* x  = (const float*)d_in[0];
    const float* c  = (const float*)d_in[1];
    const float* bb = (const float*)d_in[2];
    const int*   px = (const int*)d_in[3];
    const int*   py = (const int*)d_in[4];
    const int*   sx = (const int*)d_in[5];
    const int*   sy = (const int*)d_in[6];
    float* out = (float*)d_out;

    const int words = B_ * NIF * 2 * 2 * 8 * NY;
    reset_halo<<<(words + 255) / 256, 256, 0, stream>>>();

    void* args[] = { (void*)&x, (void*)&c, (void*)&bb, (void*)&px, (void*)&py,
                     (void*)&sx, (void*)&sy, (void*)&out };
    hipLaunchCooperativeKernel(reinterpret_cast<void*>(wave_multi),
                               dim3(B_ * NSLAB), dim3(THREADS), args, 0, stream);
}

// Round 5
// 358.691 us; speedup vs baseline: 19.9372x; 1.1933x over previous
//
#include <hip/hip_runtime.h>

// WaveRNN: damped 2D wave equation, B=16, T=256, 256x256 grid, 3 probes.
// 8 slabs per batch (128 WGs x 512 threads, cooperative). Wave w owns rows
// s*32 + 4w .. +3; lane l owns cols 4l..4l+3 (4x4 register tile).
// NO __syncthreads in the main loop. All neighbor-row exchange is tagged
// message-passing, parity double-buffered:
//   intra-WG : LDS value rows + int tag; producer writes vals, s_waitcnt
//              lgkmcnt(0), then tag (DS ops drain in order per wave, so
//              tag-visible => vals-visible). Consumer spins on tag, then reads.
//   inter-WG : 8-byte {tag,value} packets, relaxed agent-scope atomics
//              (single-copy atomic => self-describing, no fences).
// Skew between neighbors is bounded to 1 step by the mutual dependency
// (w needs w+-1's step-t row to compute t+1), which also proves the parity
// slot being overwritten (t+1 over t-1) was already consumed. No deadlock.
// Per substep: poll ghosts -> compute rows 0,3 -> publish -> compute rows 1,2.

#define B_    16
#define T_    256
#define NY    256
#define NP    3
#define NSLAB 8
#define WAVES 8
#define THREADS 512
#define NIF   (NSLAB - 1)

// [side][batch][iface][parity][j][lane]
// side0: slab i's bottom row (wave7 row3) -> consumed by slab i+1 (up ghost)
// side1: slab i+1's top row (wave0 row0)  -> consumed by slab i (down ghost)
__device__ uint64_t g_halo[2][B_][NIF][2][4][64];

__global__ void reset_halo()
{
    const int n = 2 * B_ * NIF * 2 * 4 * 64;
    int i = blockIdx.x * blockDim.x + threadIdx.x;
    if (i < n) (&g_halo[0][0][0][0][0][0])[i] = 0ull;   // tag0,val0 = step-0 data
}

#define PACK(tag, f) (((uint64_t)(uint32_t)(tag) << 32) | (uint64_t)__float_as_uint(f))

#define GPOLL(dst, side, iface, P_, TT) do { \
    uint64_t* gp_ = &g_halo[side][b][iface][P_][0][l]; \
    uint64_t a0_, a1_, a2_, a3_; bool ok_; \
    do { \
        a0_ = __hip_atomic_load(gp_ + 0 * 64, __ATOMIC_RELAXED, __HIP_MEMORY_SCOPE_AGENT); \
        a1_ = __hip_atomic_load(gp_ + 1 * 64, __ATOMIC_RELAXED, __HIP_MEMORY_SCOPE_AGENT); \
        a2_ = __hip_atomic_load(gp_ + 2 * 64, __ATOMIC_RELAXED, __HIP_MEMORY_SCOPE_AGENT); \
        a3_ = __hip_atomic_load(gp_ + 3 * 64, __ATOMIC_RELAXED, __HIP_MEMORY_SCOPE_AGENT); \
        ok_ = ((uint32_t)(a0_ >> 32) == (uint32_t)(TT)) && ((uint32_t)(a1_ >> 32) == (uint32_t)(TT)) \
           && ((uint32_t)(a2_ >> 32) == (uint32_t)(TT)) && ((uint32_t)(a3_ >> 32) == (uint32_t)(TT)); \
    } while (!ok_); \
    dst[0] = __uint_as_float((uint32_t)a0_); dst[1] = __uint_as_float((uint32_t)a1_); \
    dst[2] = __uint_as_float((uint32_t)a2_); dst[3] = __uint_as_float((uint32_t)a3_); \
} while (0)

#define GPUB(side, iface, Q_, TAG1, HROW) do { \
    uint64_t* gp_ = &g_halo[side][b][iface][Q_][0][l]; \
    __hip_atomic_store(gp_ + 0 * 64, PACK(TAG1, HROW[0]), __ATOMIC_RELAXED, __HIP_MEMORY_SCOPE_AGENT); \
    __hip_atomic_store(gp_ + 1 * 64, PACK(TAG1, HROW[1]), __ATOMIC_RELAXED, __HIP_MEMORY_SCOPE_AGENT); \
    __hip_atomic_store(gp_ + 2 * 64, PACK(TAG1, HROW[2]), __ATOMIC_RELAXED, __HIP_MEMORY_SCOPE_AGENT); \
    __hip_atomic_store(gp_ + 3 * 64, PACK(TAG1, HROW[3]), __ATOMIC_RELAXED, __HIP_MEMORY_SCOPE_AGENT); \
} while (0)

// hn = h2 + TC*(h1-h2) + CC*(s4 - 4*h1), written into H2[r] in place.
#define ROWC(H1, H2, r, UPA, DNA) do { \
    float lf_ = __shfl_up(H1[r][3], 1, 64); \
    float rt_ = __shfl_down(H1[r][0], 1, 64); \
    if (l == 0)  lf_ = 0.f; \
    if (l == 63) rt_ = 0.f; \
    _Pragma("unroll") for (int j = 0; j < 4; ++j) { \
        const float lv_ = (j == 0) ? lf_ : H1[r][j - 1]; \
        const float rv_ = (j == 3) ? rt_ : H1[r][j + 1]; \
        const float s4_ = (UPA[j] + DNA[j]) + (lv_ + rv_); \
        const float d_  = H1[r][j] - H2[r][j]; \
        const float e_  = fmaf(-4.0f, H1[r][j], s4_); \
        float v_ = fmaf(CC[r][j], e_, H2[r][j]); \
        v_ = fmaf(TC[r][j], d_, v_); \
        H2[r][j] = v_; \
    } \
} while (0)

#define SRCP(H2, r, TT) do { \
    if (srcHere && src_r == (r)) { \
        _Pragma("unroll") for (int j = 0; j < 4; ++j) \
            if (src_c == j) H2[r][j] += xbuf[TT]; \
    } \
    _Pragma("unroll") for (int qq = 0; qq < NP; ++qq) { \
        if (pHere[qq] && pr[qq] == (r)) { \
            float v_ = 0.f; \
            _Pragma("unroll") for (int j = 0; j < 4; ++j) \
                if (pc[qq] == j) v_ = H2[r][j]; \
            out[((size_t)b * T_ + (TT)) * NP + qq] = v_; \
        } \
    } \
} while (0)

// One substep: H1=h^t, H2=h^{t-1} -> h^{t+1} into H2. P_=t&1, Q_=(t+1)&1.
#define SUB(H1, H2, TT, P_, Q_) do { \
    float gu_[4], gd_[4]; \
    if (w == 0) { \
        if (s == 0) { gu_[0] = gu_[1] = gu_[2] = gu_[3] = 0.f; } \
        else GPOLL(gu_, 0, s - 1, P_, TT); \
    } else { \
        while (__hip_atomic_load(&r3t[w - 1][P_], __ATOMIC_RELAXED, __HIP_MEMORY_SCOPE_WORKGROUP) != (TT)) {} \
        asm volatile("" ::: "memory"); \
        const float4 u4_ = *reinterpret_cast<const float4*>(&r3v[w - 1][P_][y0]); \
        gu_[0] = u4_.x; gu_[1] = u4_.y; gu_[2] = u4_.z; gu_[3] = u4_.w; \
    } \
    if (w == WAVES - 1) { \
        if (s == NSLAB - 1) { gd_[0] = gd_[1] = gd_[2] = gd_[3] = 0.f; } \
        else GPOLL(gd_, 1, s, P_, TT); \
    } else { \
        while (__hip_atomic_load(&r0t[w + 1][P_], __ATOMIC_RELAXED, __HIP_MEMORY_SCOPE_WORKGROUP) != (TT)) {} \
        asm volatile("" ::: "memory"); \
        const float4 d4_ = *reinterpret_cast<const float4*>(&r0v[w + 1][P_][y0]); \
        gd_[0] = d4_.x; gd_[1] = d4_.y; gd_[2] = d4_.z; gd_[3] = d4_.w; \
    } \
    /* boundary rows first */ \
    ROWC(H1, H2, 0, gu_, H1[1]); \
    ROWC(H1, H2, 3, H1[2], gd_); \
    SRCP(H2, 0, TT); \
    SRCP(H2, 3, TT); \
    /* publish: vals, drain DS, then tags (in-order DS => tag implies vals) */ \
    if (w > 0) \
        *reinterpret_cast<float4*>(&r0v[w][Q_][y0]) = make_float4(H2[0][0], H2[0][1], H2[0][2], H2[0][3]); \
    if (w < WAVES - 1) \
        *reinterpret_cast<float4*>(&r3v[w][Q_][y0]) = make_float4(H2[3][0], H2[3][1], H2[3][2], H2[3][3]); \
    asm volatile("s_waitcnt lgkmcnt(0)" ::: "memory"); \
    if (l == 0) { \
        if (w > 0) \
            __hip_atomic_store(&r0t[w][Q_], (TT) + 1, __ATOMIC_RELAXED, __HIP_MEMORY_SCOPE_WORKGROUP); \
        if (w < WAVES - 1) \
            __hip_atomic_store(&r3t[w][Q_], (TT) + 1, __ATOMIC_RELAXED, __HIP_MEMORY_SCOPE_WORKGROUP); \
    } \
    if (w == 0 && s > 0)                 GPUB(1, s - 1, Q_, (TT) + 1, H2[0]); \
    if (w == WAVES - 1 && s < NSLAB - 1) GPUB(0, s,     Q_, (TT) + 1, H2[3]); \
    /* interior rows overlap neighbors' consumption */ \
    ROWC(H1, H2, 1, H1[0], H1[2]); \
    ROWC(H1, H2, 2, H1[1], H1[3]); \
    SRCP(H2, 1, TT); \
    SRCP(H2, 2, TT); \
} while (0)

__launch_bounds__(THREADS, 2)
__global__ void wave_multi(const float* __restrict__ xin,
                           const float* __restrict__ cin,
                           const float* __restrict__ bin,
                           const int* __restrict__ pxp,
                           const int* __restrict__ pyp,
                           const int* __restrict__ sxp,
                           const int* __restrict__ syp,
                           float* __restrict__ out)
{
    const int blk = blockIdx.x;
    const int b = blk >> 3;           // batch
    const int s = blk & 7;            // slab: rows [s*32, s*32+32)
    const int tid = threadIdx.x;
    const int w = tid >> 6;           // wave 0..7
    const int l = tid & 63;           // lane
    const int r0 = s * 32 + w * 4;    // global row of tile row 0
    const int y0 = l * 4;             // global col of tile col 0

    __shared__ float xbuf[T_];
    __shared__ float r0v[WAVES][2][NY];   // wave w's row0 values, by parity
    __shared__ float r3v[WAVES][2][NY];   // wave w's row3 values, by parity
    __shared__ int   r0t[WAVES][2];       // tags
    __shared__ int   r3t[WAVES][2];

    for (int i = tid; i < WAVES * 2 * NY; i += THREADS) {
        (&r0v[0][0][0])[i] = 0.f;
        (&r3v[0][0][0])[i] = 0.f;
    }
    if (tid < WAVES * 2) {
        const int w_ = tid >> 1, p_ = tid & 1;
        r0t[w_][p_] = (p_ == 0) ? 0 : -1;   // parity0 holds valid step-0 zeros
        r3t[w_][p_] = (p_ == 0) ? 0 : -1;
    }
    if (tid < T_) xbuf[tid] = xin[b * T_ + tid];

    // state + compressed coefficients: TC = 2*c1, CC = c1*(DT^2*c^2)
    // hn = h2 + TC*(h1-h2) + CC*(s4 - 4*h1)   [c1*c2 == 2*c1 - 1]
    float h1[4][4], h2[4][4], TC[4][4], CC[4][4];
#pragma unroll
    for (int r = 0; r < 4; ++r) {
        const float4 cv = *reinterpret_cast<const float4*>(&cin[(r0 + r) * NY + y0]);
        const float4 bv = *reinterpret_cast<const float4*>(&bin[(r0 + r) * NY + y0]);
        const float cvv[4] = {cv.x, cv.y, cv.z, cv.w};
        const float bvv[4] = {bv.x, bv.y, bv.z, bv.w};
#pragma unroll
        for (int j = 0; j < 4; ++j) {
            const float c1  = 1.0f / (1.0f + 0.25f * bvv[j]);
            const float csq = 0.25f * cvv[j] * cvv[j];
            TC[r][j] = 2.0f * c1;
            CC[r][j] = c1 * csq;
            h1[r][j] = 0.f;
            h2[r][j] = 0.f;
        }
    }

    const int sx = sxp[0], sy = syp[0];
    const bool srcHere = (sx >= r0 && sx < r0 + 4 && sy >= y0 && sy < y0 + 4);
    const int  src_r = sx - r0, src_c = sy - y0;
    bool pHere[NP];
    int  pr[NP], pc[NP];
#pragma unroll
    for (int q = 0; q < NP; ++q) {
        const int pxx = pxp[q], pyy = pyp[q];
        pHere[q] = (pxx >= r0 && pxx < r0 + 4 && pyy >= y0 && pyy < y0 + 4);
        pr[q] = pxx - r0;
        pc[q] = pyy - y0;
    }

    __syncthreads();   // the only barrier: LDS init

#pragma unroll 1
    for (int t = 0; t < T_; t += 2) {
        SUB(h1, h2, t,     0, 1);   // h^{t+1} -> h2
        SUB(h2, h1, t + 1, 1, 0);   // h^{t+2} -> h1
    }
}

extern "C" void kernel_launch(void* const* d_in, const int* in_sizes, int n_in,
                              void* d_out, int out_size, void* d_ws, size_t ws_size,
                              hipStream_t stream)
{
    const float* x  = (const float*)d_in[0];
    const float* c  = (const float*)d_in[1];
    const float* bb = (const float*)d_in[2];
    const int*   px = (const int*)d_in[3];
    const int*   py = (const int*)d_in[4];
    const int*   sx = (const int*)d_in[5];
    const int*   sy = (const int*)d_in[6];
    float* out = (float*)d_out;

    const int words = 2 * B_ * NIF * 2 * 4 * 64;
    reset_halo<<<(words + 255) / 256, 256, 0, stream>>>();

    void* args[] = { (void*)&x, (void*)&c, (void*)&bb, (void*)&px, (void*)&py,
                     (void*)&sx, (void*)&sy, (void*)&out };
    hipLaunchCooperativeKernel(reinterpret_cast<void*>(wave_multi),
                               dim3(B_ * NSLAB), dim3(THREADS), args, 0, stream);
}